// Round 1
// baseline (177.711 us; speedup 1.0000x reference)
//
#include <hip/hip_runtime.h>
#include <hip/hip_bf16.h>

// Problem constants
#define BATCH 2
#define GRP   2
#define NBG   4            // BATCH*GRP
#define CINCH 192          // input channels
#define OG    192          // output channels per group
#define HWDIM 48
#define LPIX  2304         // 48*48
#define KTAP  25           // 5x5
#define IDIM  4800         // CINCH*KTAP
#define NCHUNK 150         // IDIM/32
#define KSPLIT 2
#define CHUNKS_PER_KS 75

typedef __attribute__((ext_vector_type(4))) float  float4v;
typedef __attribute__((ext_vector_type(8))) short  short8;

// Static device scratch (avoids relying on ws_size): bf16 reordered weights + mask bits
__device__ unsigned short       g_wr[NBG * OG * IDIM];   // [bg][o][i'], i' = kk*192 + c
__device__ unsigned long long   g_m64[NBG * LPIX];       // 50 mask bits per (bg, l)

__device__ __forceinline__ unsigned short f2bf(float f) {
  union { float f; unsigned int u; } un; un.f = f;
  unsigned int u = un.u;
  return (unsigned short)((u + 0x7fffu + ((u >> 16) & 1u)) >> 16);  // RNE
}

// ---------------------------------------------------------------------------
// K1: reorder dkw (fp32, [bg][o][i=c*25+kk]) -> g_wr (bf16, [bg][o][i'=kk*192+c])
// One block per (bg,o) row; LDS-stage the fp32 row, write permuted bf16 coalesced.
__global__ void reorder_w(const float* __restrict__ dkw) {
  __shared__ float row[IDIM];
  const int blk = blockIdx.x;                 // 0..767 = bg*192 + o
  const float* src = dkw + (size_t)blk * IDIM;
  for (int i = threadIdx.x; i < IDIM; i += 256) row[i] = src[i];
  __syncthreads();
  unsigned short* dst = g_wr + (size_t)blk * IDIM;
  for (int ip = threadIdx.x; ip < IDIM; ip += 256) {
    const int kk = ip / CINCH, c = ip % CINCH;
    dst[ip] = f2bf(row[c * KTAP + kk]);
  }
}

// ---------------------------------------------------------------------------
// K2: mask bits. mask(b,g,g2,kk,l) = inbounds && tg[b,g2,hh,ww] < tg[b,g,h,w]
// (the tg.max() offset in the reference cancels; zero-padding is always masked)
__global__ void build_mask(const int* __restrict__ tg) {
  const int idx = blockIdx.x * 256 + threadIdx.x;  // 0..9215
  if (idx >= NBG * LPIX) return;
  const int bg = idx / LPIX, l = idx % LPIX;
  const int b = bg >> 1, g = bg & 1;
  const int h = l / HWDIM, w = l % HWDIM;
  const int center = tg[((b * GRP + g) * HWDIM + h) * HWDIM + w];
  unsigned long long bits = 0ull;
  #pragma unroll
  for (int g2 = 0; g2 < GRP; ++g2) {
    const int* tp = tg + (size_t)(b * GRP + g2) * LPIX;
    #pragma unroll
    for (int kk = 0; kk < KTAP; ++kk) {
      const int hh = h + kk / 5 - 2, ww = w + kk % 5 - 2;
      if (hh >= 0 && hh < HWDIM && ww >= 0 && ww < HWDIM &&
          tp[hh * HWDIM + ww] < center)
        bits |= 1ull << (g2 * KTAP + kk);
    }
  }
  g_m64[idx] = bits;
}

// ---------------------------------------------------------------------------
// K3: fused masked GEMM. Block tile: 64(o) x 128(l). 4 waves; wave w owns
// l-subtile [w*32, w*32+32) with 4x2 mfma_f32_16x16x32_bf16 (acc 64x32).
// K loop over 32-wide chunks of i' (fixed kk, fixed c-group per chunk).
// K-split=2 over chunk range, fp32 atomicAdd epilogue (out pre-zeroed).
// LDS XOR swizzle: element (row,k) -> row*32 + ((k>>3 ^ (row&3))<<3) + (k&7)
__global__ __launch_bounds__(256, 2) void gemm_masked(
    const float* __restrict__ x, const float* __restrict__ dkb,
    float* __restrict__ out) {
  __shared__ unsigned short As[64 * 32];     // [o][k]
  __shared__ unsigned short Bs[128 * 32];    // [l][k]

  const int ltile = blockIdx.x;              // 0..17
  const int otile = blockIdx.y;              // 0..2
  const int bg    = blockIdx.z >> 1;         // 0..3
  const int ks    = blockIdx.z & 1;          // K-split half
  const int b     = bg >> 1;
  const int lbase = ltile * 128, obase = otile * 64;
  const int tid = threadIdx.x, lane = tid & 63, wv = tid >> 6;

  // --- A staging coords: thread -> (o row, k-segment of 8)
  const int ao_row = tid >> 2, ak8 = tid & 3;
  const unsigned short* wsrc =
      g_wr + ((size_t)(bg * OG + obase + ao_row)) * IDIM + ak8 * 8;
  unsigned short* adst = As + ao_row * 32 + ((ak8 ^ (ao_row & 3)) << 3);

  // --- B staging coords: thread -> (l_local, 16 k's)
  const int bl   = ((wv & 1) << 6) | lane;   // 0..127
  const int bkg  = wv >> 1;                  // k in [bkg*16, bkg*16+16)
  const int lglob = lbase + bl;
  const int h = lglob / HWDIM, w = lglob % HWDIM;
  const unsigned long long mybits = g_m64[bg * LPIX + lglob];
  const float* xb = x + (size_t)b * CINCH * LPIX;
  unsigned short* bdst0 = Bs + bl * 32 + ((((bkg << 1)    ) ^ (bl & 3)) << 3);
  unsigned short* bdst1 = Bs + bl * 32 + ((((bkg << 1) | 1) ^ (bl & 3)) << 3);

  // --- fragment coords
  const int q = lane >> 4, m16 = lane & 15;

  float4v acc[4][2];
  #pragma unroll
  for (int i = 0; i < 4; ++i)
    #pragma unroll
    for (int j = 0; j < 2; ++j) acc[i][j] = (float4v)(0.0f);

  const int t0 = ks * CHUNKS_PER_KS, t1 = t0 + CHUNKS_PER_KS;
  for (int t = t0; t < t1; ++t) {
    const int kk = t / 6;                    // tap index 0..24
    const int cb = (t % 6) * 32;             // input-channel base
    const int g2 = cb / 96;                  // channel group of this chunk

    // A prefetch (16B per thread)
    const uint4 aval = *reinterpret_cast<const uint4*>(wsrc + (size_t)t * 32);

    // B: masked x gather (mask bit is uniform over the whole chunk per l)
    unsigned int pk[8];
    const int bit = (int)((mybits >> (g2 * KTAP + kk)) & 1ull);
    if (bit) {  // bit==1 implies the tap is in-bounds
      const int hh = h + kk / 5 - 2, ww = w + kk % 5 - 2;
      const float* xs = xb + (size_t)(cb + bkg * 16) * LPIX + hh * HWDIM + ww;
      float v[16];
      #pragma unroll
      for (int j = 0; j < 16; ++j) v[j] = xs[(size_t)j * LPIX];
      #pragma unroll
      for (int p = 0; p < 8; ++p)
        pk[p] = (unsigned)f2bf(v[2 * p]) | ((unsigned)f2bf(v[2 * p + 1]) << 16);
    } else {
      #pragma unroll
      for (int p = 0; p < 8; ++p) pk[p] = 0u;
    }

    __syncthreads();   // previous iteration's frag reads done
    *reinterpret_cast<uint4*>(adst) = aval;
    uint4 b0; b0.x = pk[0]; b0.y = pk[1]; b0.z = pk[2]; b0.w = pk[3];
    uint4 b1; b1.x = pk[4]; b1.y = pk[5]; b1.z = pk[6]; b1.w = pk[7];
    *reinterpret_cast<uint4*>(bdst0) = b0;
    *reinterpret_cast<uint4*>(bdst1) = b1;
    __syncthreads();   // tiles visible

    short8 af[4], bfr[2];
    #pragma unroll
    for (int i = 0; i < 4; ++i) {
      const int r = i * 16 + m16;            // A row: m = lane&15
      af[i] = *reinterpret_cast<const short8*>(As + r * 32 + ((q ^ (r & 3)) << 3));
    }
    #pragma unroll
    for (int j = 0; j < 2; ++j) {
      const int cl = wv * 32 + j * 16 + m16; // B col: n = lane&15
      bfr[j] = *reinterpret_cast<const short8*>(Bs + cl * 32 + ((q ^ (cl & 3)) << 3));
    }
    #pragma unroll
    for (int i = 0; i < 4; ++i)
      #pragma unroll
      for (int j = 0; j < 2; ++j)
        acc[i][j] = __builtin_amdgcn_mfma_f32_16x16x32_bf16(af[i], bfr[j], acc[i][j], 0, 0, 0);
  }

  // Epilogue: C/D layout col = lane&15, row = q*4 + reg. Bias added by ks==0 only.
  #pragma unroll
  for (int i = 0; i < 4; ++i) {
    const int og = obase + i * 16 + q * 4;
    #pragma unroll
    for (int j = 0; j < 2; ++j) {
      const int cl = lbase + wv * 32 + j * 16 + m16;
      #pragma unroll
      for (int r = 0; r < 4; ++r) {
        float v = acc[i][j][r];
        if (ks == 0) v += dkb[bg * OG + og + r];
        atomicAdd(&out[(size_t)(bg * OG + og + r) * LPIX + cl], v);
      }
    }
  }
}

// ---------------------------------------------------------------------------
extern "C" void kernel_launch(void* const* d_in, const int* in_sizes, int n_in,
                              void* d_out, int out_size, void* d_ws, size_t ws_size,
                              hipStream_t stream) {
  const float* x   = (const float*)d_in[0];
  const int*   tg  = (const int*)d_in[1];
  const float* dkw = (const float*)d_in[2];
  const float* dkb = (const float*)d_in[3];
  float* out = (float*)d_out;

  reorder_w<<<dim3(NBG * OG), 256, 0, stream>>>(dkw);
  build_mask<<<dim3((NBG * LPIX + 255) / 256), 256, 0, stream>>>(tg);
  hipMemsetAsync(d_out, 0, (size_t)out_size * sizeof(float), stream);
  gemm_masked<<<dim3(18, 3, NBG * KSPLIT), 256, 0, stream>>>(x, dkb, out);
}

// Round 2
// 150.667 us; speedup vs baseline: 1.1795x; 1.1795x over previous
//
#include <hip/hip_runtime.h>
#include <hip/hip_bf16.h>

// Problem constants
#define BATCH 2
#define GRP   2
#define NBG   4            // BATCH*GRP
#define CINCH 192          // input channels
#define OG    192          // output channels per group
#define HWDIM 48
#define LPIX  2304         // 48*48
#define KTAP  25           // 5x5
#define IDIM  4800         // CINCH*KTAP
#define NCHUNK 150         // IDIM/32
#define KSPLIT 5           // 5 taps per split (150/5 = 30 chunks)
#define TAPS_PER_KS 5

typedef __attribute__((ext_vector_type(4))) float  float4v;
typedef __attribute__((ext_vector_type(8))) short  short8;

// Static device scratch: chunk-major bf16 weights, bf16 transposed x, mask bits
__device__ unsigned short     g_wr[NBG * NCHUNK * OG * 32]; // [bg][t][o][k32]
__device__ unsigned short     g_xt[BATCH * LPIX * CINCH];   // [b][l][c] bf16
__device__ unsigned long long g_m64[NBG * LPIX];            // 50 mask bits per (bg,l)

__device__ __forceinline__ unsigned short f2bf(float f) {
  union { float f; unsigned int u; } un; un.f = f;
  unsigned int u = un.u;
  return (unsigned short)((u + 0x7fffu + ((u >> 16) & 1u)) >> 16);  // RNE
}

// ---------------------------------------------------------------------------
// K0: transpose+convert x fp32 [b][c][l] -> bf16 g_xt [b][l][c].
// 64c x 64l tiles via LDS (pad 66 shorts -> conflict-free transpose).
__global__ void transpose_x(const float* __restrict__ x) {
  __shared__ unsigned short tile[64 * 66];
  const int c0 = blockIdx.x * 64, l0 = blockIdx.y * 64, b = blockIdx.z;
  const int tid = threadIdx.x;
  #pragma unroll
  for (int it = 0; it < 16; ++it) {
    const int idx = it * 256 + tid;
    const int cl = idx >> 6, ll = idx & 63;
    tile[cl * 66 + ll] =
        f2bf(x[((size_t)b * CINCH + c0 + cl) * LPIX + l0 + ll]);
  }
  __syncthreads();
  #pragma unroll
  for (int it = 0; it < 16; ++it) {
    const int idx = it * 256 + tid;
    const int ll = idx >> 6, cl = idx & 63;
    g_xt[((size_t)b * LPIX + l0 + ll) * CINCH + c0 + cl] = tile[cl * 66 + ll];
  }
}

// ---------------------------------------------------------------------------
// K1: reorder dkw (fp32, [bg][o][i=c*25+kk]) -> g_wr (bf16, chunk-major
// [bg][t][o][k]), where i' = kk*192 + c, t = i'/32, k = i'%32.
__global__ void reorder_w(const float* __restrict__ dkw) {
  __shared__ float row[IDIM];
  const int blk = blockIdx.x;                 // bg*192 + o
  const int bg = blk / OG, o = blk % OG;
  const float* src = dkw + (size_t)blk * IDIM;
  for (int i = threadIdx.x; i < IDIM; i += 256) row[i] = src[i];
  __syncthreads();
  for (int ip = threadIdx.x; ip < IDIM; ip += 256) {
    const int kk = ip / CINCH, c = ip % CINCH;
    const int t = ip >> 5, k = ip & 31;
    g_wr[(((size_t)bg * NCHUNK + t) * OG + o) * 32 + k] = f2bf(row[c * KTAP + kk]);
  }
}

// ---------------------------------------------------------------------------
// K2: mask bits. mask(b,g,g2,kk,l) = inbounds && tg[b,g2,hh,ww] < tg[b,g,h,w]
// (the tg.max() offset in the reference cancels; zero-padding is always masked)
__global__ void build_mask(const int* __restrict__ tg) {
  const int idx = blockIdx.x * 256 + threadIdx.x;  // 0..9215
  if (idx >= NBG * LPIX) return;
  const int bg = idx / LPIX, l = idx % LPIX;
  const int b = bg >> 1, g = bg & 1;
  const int h = l / HWDIM, w = l % HWDIM;
  const int center = tg[((b * GRP + g) * HWDIM + h) * HWDIM + w];
  unsigned long long bits = 0ull;
  #pragma unroll
  for (int g2 = 0; g2 < GRP; ++g2) {
    const int* tp = tg + (size_t)(b * GRP + g2) * LPIX;
    #pragma unroll
    for (int kk = 0; kk < KTAP; ++kk) {
      const int hh = h + kk / 5 - 2, ww = w + kk % 5 - 2;
      if (hh >= 0 && hh < HWDIM && ww >= 0 && ww < HWDIM &&
          tp[hh * HWDIM + ww] < center)
        bits |= 1ull << (g2 * KTAP + kk);
    }
  }
  g_m64[idx] = bits;
}

// ---------------------------------------------------------------------------
// K3: fused masked GEMM, NO LDS / NO barriers. Block tile 64(o) x 128(l),
// 4 waves, wave w owns l-subtile [w*32, +32): 4x2 mfma_f32_16x16x32_bf16.
// Fragments load DIRECTLY from global (chunk-major A blob is L1-resident and
// shared by all 4 waves; x_t rows are L2-resident). K-split over taps:
// block handles 5 taps x 6 chunks; mask bit + tap offset uniform per tap.
// fp32 atomicAdd epilogue (out pre-zeroed), bias added by ks==0.
__global__ __launch_bounds__(256, 4) void gemm_masked(
    const float* __restrict__ dkb, float* __restrict__ out) {
  const int ltile = blockIdx.x;              // 0..17
  const int otile = blockIdx.y;              // 0..2
  const int bg    = blockIdx.z & 3;
  const int ks    = blockIdx.z >> 2;         // 0..4 (tap-split)
  const int b     = bg >> 1;
  const int lbase = ltile * 128, obase = otile * 64;
  const int tid = threadIdx.x, lane = tid & 63, wv = tid >> 6;
  const int q = lane >> 4, m16 = lane & 15;

  const int l0 = lbase + wv * 32 + m16;      // col for j=0 frag
  const int l1 = l0 + 16;                    // col for j=1 frag
  const unsigned long long bits0 = g_m64[bg * LPIX + l0];
  const unsigned long long bits1 = g_m64[bg * LPIX + l1];
  const unsigned short* xrow = g_xt + (size_t)b * LPIX * CINCH + q * 8;

  float4v acc[4][2];
  #pragma unroll
  for (int i = 0; i < 4; ++i)
    #pragma unroll
    for (int j = 0; j < 2; ++j) acc[i][j] = (float4v)(0.0f);

  const short8 zfrag = (short8)(short)0;

  for (int kt = 0; kt < TAPS_PER_KS; ++kt) {
    const int kk = ks * TAPS_PER_KS + kt;    // tap 0..24
    const int doff = (kk / 5 - 2) * HWDIM + (kk % 5 - 2);
    const size_t xoff0 = (size_t)(l0 + doff) * CINCH;
    const size_t xoff1 = (size_t)(l1 + doff) * CINCH;
    #pragma unroll
    for (int ci = 0; ci < 6; ++ci) {
      const int t = kk * 6 + ci;
      const int bitpos = (ci / 3) * KTAP + kk;
      const unsigned short* ab =
          g_wr + (((size_t)bg * NCHUNK + t) * OG + obase) * 32 + q * 8;
      short8 af[4];
      #pragma unroll
      for (int i = 0; i < 4; ++i)
        af[i] = *reinterpret_cast<const short8*>(ab + (i * 16 + m16) * 32);
      short8 bf0 = zfrag, bf1 = zfrag;
      if ((bits0 >> bitpos) & 1ull)
        bf0 = *reinterpret_cast<const short8*>(xrow + xoff0 + ci * 32);
      if ((bits1 >> bitpos) & 1ull)
        bf1 = *reinterpret_cast<const short8*>(xrow + xoff1 + ci * 32);
      #pragma unroll
      for (int i = 0; i < 4; ++i) {
        acc[i][0] = __builtin_amdgcn_mfma_f32_16x16x32_bf16(af[i], bf0, acc[i][0], 0, 0, 0);
        acc[i][1] = __builtin_amdgcn_mfma_f32_16x16x32_bf16(af[i], bf1, acc[i][1], 0, 0, 0);
      }
    }
  }

  // Epilogue: C/D layout col = lane&15, row = q*4 + reg.
  #pragma unroll
  for (int i = 0; i < 4; ++i) {
    const int og = obase + i * 16 + q * 4;
    #pragma unroll
    for (int j = 0; j < 2; ++j) {
      const int cl = lbase + wv * 32 + j * 16 + m16;
      #pragma unroll
      for (int r = 0; r < 4; ++r) {
        float v = acc[i][j][r];
        if (ks == 0) v += dkb[bg * OG + og + r];
        atomicAdd(&out[(size_t)(bg * OG + og + r) * LPIX + cl], v);
      }
    }
  }
}

// ---------------------------------------------------------------------------
extern "C" void kernel_launch(void* const* d_in, const int* in_sizes, int n_in,
                              void* d_out, int out_size, void* d_ws, size_t ws_size,
                              hipStream_t stream) {
  const float* x   = (const float*)d_in[0];
  const int*   tg  = (const int*)d_in[1];
  const float* dkw = (const float*)d_in[2];
  const float* dkb = (const float*)d_in[3];
  float* out = (float*)d_out;

  transpose_x<<<dim3(CINCH / 64, LPIX / 64, BATCH), 256, 0, stream>>>(x);
  reorder_w<<<dim3(NBG * OG), 256, 0, stream>>>(dkw);
  build_mask<<<dim3((NBG * LPIX + 255) / 256), 256, 0, stream>>>(tg);
  hipMemsetAsync(d_out, 0, (size_t)out_size * sizeof(float), stream);
  gemm_masked<<<dim3(18, 3, NBG * KSPLIT), 256, 0, stream>>>(dkb, out);
}